// Round 2
// baseline (1282.715 us; speedup 1.0000x reference)
//
#include <hip/hip_runtime.h>

typedef unsigned short u16;
typedef __attribute__((ext_vector_type(8))) short short8;
typedef __attribute__((ext_vector_type(4))) short short4v;
typedef __attribute__((ext_vector_type(4))) float floatx4;

#define HD 1024
#define SEQ 4096

__device__ inline u16 f2bf(float f) {
    union { float f; unsigned int i; } c; c.f = f;
    unsigned int r = c.i + 0x7fffu + ((c.i >> 16) & 1u);
    return (u16)(r >> 16);
}

// ---------------- Kernel A: x f32 -> bf16 ----------------
__global__ __launch_bounds__(256) void cvt_kernel(const float* __restrict__ in,
                                                  u16* __restrict__ out, int n4) {
    int idx = blockIdx.x * 256 + threadIdx.x;
    int stride = gridDim.x * 256;
    for (int i = idx; i < n4; i += stride) {
        floatx4 v = ((const floatx4*)in)[i];
        short4v o;
        o[0] = (short)f2bf(v[0]); o[1] = (short)f2bf(v[1]);
        o[2] = (short)f2bf(v[2]); o[3] = (short)f2bf(v[3]);
        ((short4v*)out)[i] = o;
    }
}

// ---------------- Kernel 0: W f32 [k][n] -> Wt bf16 [n][k], 3 matrices ----------------
__global__ __launch_bounds__(256) void wt_kernel(const float* __restrict__ Wq,
                                                 const float* __restrict__ Wk,
                                                 const float* __restrict__ Wv,
                                                 u16* __restrict__ wt) {
    __shared__ u16 tile[64 * 65];
    int z = blockIdx.z;
    const float* W = (z == 0) ? Wq : ((z == 1) ? Wk : Wv);
    u16* out = wt + (size_t)z * HD * HD;
    int k0 = blockIdx.x * 64, n0 = blockIdx.y * 64;
    int t = threadIdx.x;
    // load 64x64 f32 tile, convert to bf16
    int r = t >> 4, c4 = (t & 15) * 4;
    for (int h = 0; h < 4; ++h) {
        int row = r + h * 16;
        floatx4 v = *(const floatx4*)(W + (size_t)(k0 + row) * HD + n0 + c4);
        tile[row * 65 + c4 + 0] = f2bf(v[0]);
        tile[row * 65 + c4 + 1] = f2bf(v[1]);
        tile[row * 65 + c4 + 2] = f2bf(v[2]);
        tile[row * 65 + c4 + 3] = f2bf(v[3]);
    }
    __syncthreads();
    // store transposed: out[n][k] = W[k][n]
    int r2 = t >> 3, c8 = (t & 7) * 8;
    union { short8 v; u16 u[8]; } buf;
    for (int h = 0; h < 2; ++h) {
        int rr = r2 + h * 32;
        #pragma unroll
        for (int i = 0; i < 8; ++i) buf.u[i] = tile[(c8 + i) * 65 + rr];
        *(short8*)(out + (size_t)(n0 + rr) * HD + k0 + c8) = buf.v;
    }
}

// ---------------- Kernel 1: QKV GEMM (bf16 in, f32 bias, bf16 out) ----------------
// C[m][n] = sum_k xb[m][k] * W[k][n] + bias[n]; z selects Q/K/V.
// z==2 (V): store transposed per batch: vt[(b*HD + n)*SEQ + s], m = b*SEQ + s.
__global__ __launch_bounds__(256, 2) void qkv_gemm(const u16* __restrict__ x,
                                                   const u16* __restrict__ wt,
                                                   const float* __restrict__ bq,
                                                   const float* __restrict__ bk,
                                                   const float* __restrict__ bv,
                                                   u16* __restrict__ qb,
                                                   u16* __restrict__ kbuf,
                                                   u16* __restrict__ vtb) {
    __shared__ __align__(16) u16 sA[128 * 40];  // pad 40: bank rotation 20 -> 2-way (free)
    __shared__ __align__(16) u16 sB[128 * 40];
    int z = blockIdx.z;
    const u16* Bt = wt + (size_t)z * HD * HD;
    const float* bias = (z == 0) ? bq : ((z == 1) ? bk : bv);
    int m0 = blockIdx.x * 128, n0 = blockIdx.y * 128;
    int t = threadIdx.x, lane = t & 63, w = t >> 6;
    int quad = lane >> 4, l16 = lane & 15;
    int wm = w >> 1, wn = w & 1;
    floatx4 acc[4][4] = {};
    int sr = t >> 2, sc = (t & 3) * 8;

    for (int k0 = 0; k0 < HD; k0 += 32) {
        #pragma unroll
        for (int h = 0; h < 2; ++h) {
            int row = sr + h * 64;
            *(short8*)&sA[row * 40 + sc] = *(const short8*)&x[(size_t)(m0 + row) * HD + k0 + sc];
            *(short8*)&sB[row * 40 + sc] = *(const short8*)&Bt[(size_t)(n0 + row) * HD + k0 + sc];
        }
        __syncthreads();
        short8 af[4], bfr[4];
        #pragma unroll
        for (int i = 0; i < 4; ++i) af[i] = *(const short8*)&sA[(wm * 64 + i * 16 + l16) * 40 + quad * 8];
        #pragma unroll
        for (int j = 0; j < 4; ++j) bfr[j] = *(const short8*)&sB[(wn * 64 + j * 16 + l16) * 40 + quad * 8];
        #pragma unroll
        for (int i = 0; i < 4; ++i)
            #pragma unroll
            for (int j = 0; j < 4; ++j)
                acc[i][j] = __builtin_amdgcn_mfma_f32_16x16x32_bf16(af[i], bfr[j], acc[i][j], 0, 0, 0);
        __syncthreads();
    }

    #pragma unroll
    for (int j = 0; j < 4; ++j) {
        int n = n0 + wn * 64 + j * 16 + l16;
        float bb = bias[n];
        #pragma unroll
        for (int i = 0; i < 4; ++i) {
            #pragma unroll
            for (int rr = 0; rr < 4; ++rr) {
                int m = m0 + wm * 64 + i * 16 + quad * 4 + rr;
                u16 h = f2bf(acc[i][j][rr] + bb);
                if (z == 0) {
                    qb[(size_t)m * HD + n] = h;
                } else if (z == 1) {
                    kbuf[(size_t)m * HD + n] = h;
                } else {
                    int b = m >> 12, s = m & 4095;
                    vtb[((size_t)(b * HD + n)) * SEQ + s] = h;
                }
            }
        }
    }
}

// ---------------- Kernel 2: flash attention (bf16 in, f32 out) ----------------
// Grid: 256 blocks (b in [0,4), q-tile of 64 rows). 4 waves.
__global__ __launch_bounds__(256, 1) void flash_kernel(const u16* __restrict__ q,
                                                       const u16* __restrict__ k,
                                                       const u16* __restrict__ vt,
                                                       float* __restrict__ out) {
    __shared__ __align__(16) u16 q_lds[64 * 1032];  // stride 1032: 16B aligned rows
    __shared__ float Sc[64 * 68];
    __shared__ __align__(16) u16 Pb[64 * 80];
    __shared__ float m_st[64], l_st[64], al_st[64];

    int t = threadIdx.x, lane = t & 63, w = t >> 6;
    int quad = lane >> 4, l16 = lane & 15;
    int bid = blockIdx.x;
    int b = bid >> 6, q0 = (bid & 63) * 64;

    // stage Q tile [64 x 1024]
    for (int i = t; i < 64 * 128; i += 256) {
        int r = i >> 7, c8 = (i & 127) * 8;
        *(short8*)&q_lds[r * 1032 + c8] =
            *(const short8*)&q[((size_t)(b * SEQ + q0 + r)) * HD + c8];
    }
    if (t < 64) { m_st[t] = -1e30f; l_st[t] = 0.f; }
    floatx4 o_acc[4][16] = {};
    __syncthreads();

    const u16* kwave = k + ((size_t)(b * SEQ + w * 16 + l16)) * HD + quad * 8;
    const u16* vwave = vt + ((size_t)(b * HD + w * 256 + l16)) * SEQ + quad * 8;
    int r2 = w * 16 + (lane >> 2);
    int cg = (lane & 3) * 16;

    for (int tt = 0; tt < 64; ++tt) {
        int kb = tt * 64;
        // ---- phase 1: S = Q K^T (this wave's 16 k-cols) ----
        floatx4 s_acc[4] = {};
        const u16* kp = kwave + (size_t)kb * HD;
        #pragma unroll 8
        for (int ks = 0; ks < 32; ++ks) {
            short8 kf = *(const short8*)(kp + ks * 32);
            #pragma unroll
            for (int rb = 0; rb < 4; ++rb) {
                short8 qf = *(const short8*)&q_lds[(rb * 16 + l16) * 1032 + ks * 32 + quad * 8];
                s_acc[rb] = __builtin_amdgcn_mfma_f32_16x16x32_bf16(qf, kf, s_acc[rb], 0, 0, 0);
            }
        }
        #pragma unroll
        for (int rb = 0; rb < 4; ++rb)
            #pragma unroll
            for (int rr = 0; rr < 4; ++rr)
                Sc[(rb * 16 + quad * 4 + rr) * 68 + w * 16 + l16] = s_acc[rb][rr] * 0.03125f;
        __syncthreads();

        // ---- phase 2: online softmax (row r2, 16 cols per lane) ----
        float sv[16];
        float mloc = -1e30f;
        #pragma unroll
        for (int i = 0; i < 16; ++i) { sv[i] = Sc[r2 * 68 + cg + i]; mloc = fmaxf(mloc, sv[i]); }
        mloc = fmaxf(mloc, __shfl_xor(mloc, 1));
        mloc = fmaxf(mloc, __shfl_xor(mloc, 2));
        float m_old = m_st[r2];
        float m_new = fmaxf(m_old, mloc);
        float alpha = __expf(m_old - m_new);
        float sum = 0.f;
        #pragma unroll
        for (int i = 0; i < 16; ++i) {
            float p = __expf(sv[i] - m_new);
            sum += p;
            Pb[r2 * 80 + cg + i] = f2bf(p);
        }
        sum += __shfl_xor(sum, 1);
        sum += __shfl_xor(sum, 2);
        if ((lane & 3) == 0) {
            m_st[r2] = m_new;
            l_st[r2] = l_st[r2] * alpha + sum;
            al_st[r2] = alpha;
        }
        __syncthreads();

        // ---- phase 3: O = O*alpha + P V (this wave's 256 d-cols) ----
        #pragma unroll
        for (int rb = 0; rb < 4; ++rb) {
            float a0 = al_st[rb * 16 + quad * 4 + 0];
            float a1 = al_st[rb * 16 + quad * 4 + 1];
            float a2 = al_st[rb * 16 + quad * 4 + 2];
            float a3 = al_st[rb * 16 + quad * 4 + 3];
            #pragma unroll
            for (int dt = 0; dt < 16; ++dt) {
                o_acc[rb][dt][0] *= a0;
                o_acc[rb][dt][1] *= a1;
                o_acc[rb][dt][2] *= a2;
                o_acc[rb][dt][3] *= a3;
            }
        }
        short8 pf[4][2];
        #pragma unroll
        for (int rb = 0; rb < 4; ++rb)
            #pragma unroll
            for (int ks = 0; ks < 2; ++ks)
                pf[rb][ks] = *(const short8*)&Pb[(rb * 16 + l16) * 80 + ks * 32 + quad * 8];
        const u16* vp = vwave + kb;
        #pragma unroll
        for (int dt = 0; dt < 16; ++dt) {
            short8 vf0 = *(const short8*)(vp + (size_t)dt * 16 * SEQ);
            short8 vf1 = *(const short8*)(vp + (size_t)dt * 16 * SEQ + 32);
            #pragma unroll
            for (int rb = 0; rb < 4; ++rb) {
                o_acc[rb][dt] = __builtin_amdgcn_mfma_f32_16x16x32_bf16(pf[rb][0], vf0, o_acc[rb][dt], 0, 0, 0);
                o_acc[rb][dt] = __builtin_amdgcn_mfma_f32_16x16x32_bf16(pf[rb][1], vf1, o_acc[rb][dt], 0, 0, 0);
            }
        }
        // next iteration's barrier #1 (after Sc writes) orders phase-3 reads of
        // Pb/al_st against the next phase-2 writes; phase 1 touches only Sc/q_lds.
    }

    // epilogue: O /= l, write f32
    #pragma unroll
    for (int rb = 0; rb < 4; ++rb) {
        #pragma unroll
        for (int rr = 0; rr < 4; ++rr) {
            int row = rb * 16 + quad * 4 + rr;
            float linv = 1.f / l_st[row];
            #pragma unroll
            for (int dt = 0; dt < 16; ++dt) {
                out[((size_t)(b * SEQ + q0 + row)) * HD + w * 256 + dt * 16 + l16] =
                    o_acc[rb][dt][rr] * linv;
            }
        }
    }
}

extern "C" void kernel_launch(void* const* d_in, const int* in_sizes, int n_in,
                              void* d_out, int out_size, void* d_ws, size_t ws_size,
                              hipStream_t stream) {
    const float* x  = (const float*)d_in[0];
    const float* Wq = (const float*)d_in[1];
    const float* bq = (const float*)d_in[2];
    const float* Wk = (const float*)d_in[3];
    const float* bk = (const float*)d_in[4];
    const float* Wv = (const float*)d_in[5];
    const float* bv = (const float*)d_in[6];
    float* out = (float*)d_out;

    char* ws = (char*)d_ws;
    u16* xb  = (u16*)ws;                                   // 32 MB (x as bf16)
    u16* wt  = (u16*)(ws + (size_t)32 * 1024 * 1024);      // 6 MB (3 x 1024^2 bf16)
    u16* qb  = (u16*)(ws + (size_t)38 * 1024 * 1024);      // 32 MB
    u16* kb  = (u16*)(ws + (size_t)70 * 1024 * 1024);      // 32 MB
    u16* vtb = (u16*)(ws + (size_t)102 * 1024 * 1024);     // 32 MB (V transposed per batch)

    cvt_kernel<<<dim3(4096), 256, 0, stream>>>(x, xb, (4 * SEQ * HD) / 4);
    wt_kernel<<<dim3(16, 16, 3), 256, 0, stream>>>(Wq, Wk, Wv, wt);
    qkv_gemm<<<dim3(128, 8, 3), 256, 0, stream>>>(xb, wt, bq, bk, bv, qb, kb, vtb);
    flash_kernel<<<dim3(256), 256, 0, stream>>>(qb, kb, vtb, out);
}

// Round 3
// 1207.946 us; speedup vs baseline: 1.0619x; 1.0619x over previous
//
#include <hip/hip_runtime.h>

typedef unsigned short u16;
typedef __attribute__((ext_vector_type(8))) short short8;
typedef __attribute__((ext_vector_type(4))) short short4v;
typedef __attribute__((ext_vector_type(4))) float floatx4;

#define HD 1024
#define SEQ 4096

__device__ inline u16 f2bf(float f) {
    union { float f; unsigned int i; } c; c.f = f;
    unsigned int r = c.i + 0x7fffu + ((c.i >> 16) & 1u);
    return (u16)(r >> 16);
}

// ---------------- Kernel A: x f32 -> bf16 ----------------
__global__ __launch_bounds__(256) void cvt_kernel(const float* __restrict__ in,
                                                  u16* __restrict__ out, int n4) {
    int idx = blockIdx.x * 256 + threadIdx.x;
    int stride = gridDim.x * 256;
    for (int i = idx; i < n4; i += stride) {
        floatx4 v = ((const floatx4*)in)[i];
        short4v o;
        o[0] = (short)f2bf(v[0]); o[1] = (short)f2bf(v[1]);
        o[2] = (short)f2bf(v[2]); o[3] = (short)f2bf(v[3]);
        ((short4v*)out)[i] = o;
    }
}

// ---------------- Kernel 0: W f32 [k][n] -> Wt bf16 [n][k], 3 matrices ----------------
__global__ __launch_bounds__(256) void wt_kernel(const float* __restrict__ Wq,
                                                 const float* __restrict__ Wk,
                                                 const float* __restrict__ Wv,
                                                 u16* __restrict__ wt) {
    __shared__ u16 tile[64 * 65];
    int z = blockIdx.z;
    const float* W = (z == 0) ? Wq : ((z == 1) ? Wk : Wv);
    u16* out = wt + (size_t)z * HD * HD;
    int k0 = blockIdx.x * 64, n0 = blockIdx.y * 64;
    int t = threadIdx.x;
    int r = t >> 4, c4 = (t & 15) * 4;
    for (int h = 0; h < 4; ++h) {
        int row = r + h * 16;
        floatx4 v = *(const floatx4*)(W + (size_t)(k0 + row) * HD + n0 + c4);
        tile[row * 65 + c4 + 0] = f2bf(v[0]);
        tile[row * 65 + c4 + 1] = f2bf(v[1]);
        tile[row * 65 + c4 + 2] = f2bf(v[2]);
        tile[row * 65 + c4 + 3] = f2bf(v[3]);
    }
    __syncthreads();
    int r2 = t >> 3, c8 = (t & 7) * 8;
    union { short8 v; u16 u[8]; } buf;
    for (int h = 0; h < 2; ++h) {
        int rr = r2 + h * 32;
        #pragma unroll
        for (int i = 0; i < 8; ++i) buf.u[i] = tile[(c8 + i) * 65 + rr];
        *(short8*)(out + (size_t)(n0 + rr) * HD + k0 + c8) = buf.v;
    }
}

// ---------------- Kernel 1: QKV GEMM (bf16 in, f32 bias, bf16 out) ----------------
__global__ __launch_bounds__(256, 2) void qkv_gemm(const u16* __restrict__ x,
                                                   const u16* __restrict__ wt,
                                                   const float* __restrict__ bq,
                                                   const float* __restrict__ bk,
                                                   const float* __restrict__ bv,
                                                   u16* __restrict__ qb,
                                                   u16* __restrict__ kbuf,
                                                   u16* __restrict__ vtb) {
    __shared__ __align__(16) u16 sA[128 * 40];
    __shared__ __align__(16) u16 sB[128 * 40];
    int z = blockIdx.z;
    const u16* Bt = wt + (size_t)z * HD * HD;
    const float* bias = (z == 0) ? bq : ((z == 1) ? bk : bv);
    int m0 = blockIdx.x * 128, n0 = blockIdx.y * 128;
    int t = threadIdx.x, lane = t & 63, w = t >> 6;
    int quad = lane >> 4, l16 = lane & 15;
    int wm = w >> 1, wn = w & 1;
    floatx4 acc[4][4] = {};
    int sr = t >> 2, sc = (t & 3) * 8;

    for (int k0 = 0; k0 < HD; k0 += 32) {
        #pragma unroll
        for (int h = 0; h < 2; ++h) {
            int row = sr + h * 64;
            *(short8*)&sA[row * 40 + sc] = *(const short8*)&x[(size_t)(m0 + row) * HD + k0 + sc];
            *(short8*)&sB[row * 40 + sc] = *(const short8*)&Bt[(size_t)(n0 + row) * HD + k0 + sc];
        }
        __syncthreads();
        short8 af[4], bfr[4];
        #pragma unroll
        for (int i = 0; i < 4; ++i) af[i] = *(const short8*)&sA[(wm * 64 + i * 16 + l16) * 40 + quad * 8];
        #pragma unroll
        for (int j = 0; j < 4; ++j) bfr[j] = *(const short8*)&sB[(wn * 64 + j * 16 + l16) * 40 + quad * 8];
        #pragma unroll
        for (int i = 0; i < 4; ++i)
            #pragma unroll
            for (int j = 0; j < 4; ++j)
                acc[i][j] = __builtin_amdgcn_mfma_f32_16x16x32_bf16(af[i], bfr[j], acc[i][j], 0, 0, 0);
        __syncthreads();
    }

    #pragma unroll
    for (int j = 0; j < 4; ++j) {
        int n = n0 + wn * 64 + j * 16 + l16;
        float bb = bias[n];
        #pragma unroll
        for (int i = 0; i < 4; ++i) {
            #pragma unroll
            for (int rr = 0; rr < 4; ++rr) {
                int m = m0 + wm * 64 + i * 16 + quad * 4 + rr;
                u16 h = f2bf(acc[i][j][rr] + bb);
                if (z == 0) {
                    qb[(size_t)m * HD + n] = h;
                } else if (z == 1) {
                    kbuf[(size_t)m * HD + n] = h;
                } else {
                    int b = m >> 12, s = m & 4095;
                    vtb[((size_t)(b * HD + n)) * SEQ + s] = h;
                }
            }
        }
    }
}

// ---------------- Kernel 2: flash attention (bf16 in, f32 out) ----------------
// Mq=32 per block, grid 512 (2 blocks/CU), 4 waves, 2 waves/SIMD resident.
// Phase1: wave w computes S[32q x 16k] (k-cols w*16..) -> Sc (scaled).
// Phase2: online softmax, 8 lanes/row x 8 cols, P (bf16) -> Pb LDS.
// Phase3: wave w owns d-chunk w*256; O[32 x 256] in 128 VGPRs.
__global__ __launch_bounds__(256, 2) void flash_kernel(const u16* __restrict__ q,
                                                       const u16* __restrict__ k,
                                                       const u16* __restrict__ vt,
                                                       float* __restrict__ out) {
    __shared__ __align__(16) u16 q_lds[32 * 1032];  // row stride 2064B = 129*16B (odd) -> conflict-free b128
    __shared__ float Sc[32 * 65];                    // stride 65: reads (r+8c+i)%32 cover all banks -> 2-way
    __shared__ __align__(16) u16 Pb[32 * 80];
    __shared__ float m_st[32], l_st[32], al_st[32];

    int t = threadIdx.x, lane = t & 63, w = t >> 6;
    int quad = lane >> 4, l16 = lane & 15;
    int bid = blockIdx.x;
    int b = bid >> 7, q0 = (bid & 127) * 32;

    // stage Q tile [32 x 1024]
    for (int i = t; i < 32 * 128; i += 256) {
        int r = i >> 7, c8 = (i & 127) * 8;
        *(short8*)&q_lds[r * 1032 + c8] =
            *(const short8*)&q[((size_t)(b * SEQ + q0 + r)) * HD + c8];
    }
    if (t < 32) { m_st[t] = -1e30f; l_st[t] = 0.f; }
    floatx4 o_acc[2][16] = {};
    __syncthreads();

    const u16* kwave = k + ((size_t)(b * SEQ + w * 16 + l16)) * HD + quad * 8;
    const u16* vwave = vt + ((size_t)(b * HD + w * 256 + l16)) * SEQ + quad * 8;
    int r2 = w * 8 + (lane >> 3);     // 32 rows, 8 lanes each
    int cg = (lane & 7) * 8;          // 8 cols per lane

    for (int tt = 0; tt < 64; ++tt) {
        int kb = tt * 64;
        // ---- phase 1: S = Q K^T (this wave's 16 k-cols) ----
        floatx4 s_acc[2] = {};
        const u16* kp = kwave + (size_t)kb * HD;
        #pragma unroll 8
        for (int ks = 0; ks < 32; ++ks) {
            short8 kf = *(const short8*)(kp + ks * 32);
            #pragma unroll
            for (int rb = 0; rb < 2; ++rb) {
                short8 qf = *(const short8*)&q_lds[(rb * 16 + l16) * 1032 + ks * 32 + quad * 8];
                s_acc[rb] = __builtin_amdgcn_mfma_f32_16x16x32_bf16(qf, kf, s_acc[rb], 0, 0, 0);
            }
        }
        #pragma unroll
        for (int rb = 0; rb < 2; ++rb)
            #pragma unroll
            for (int rr = 0; rr < 4; ++rr)
                Sc[(rb * 16 + quad * 4 + rr) * 65 + w * 16 + l16] = s_acc[rb][rr] * 0.03125f;
        __syncthreads();

        // ---- phase 2: online softmax (row r2, 8 cols per lane) ----
        float sv[8];
        float mloc = -1e30f;
        #pragma unroll
        for (int i = 0; i < 8; ++i) { sv[i] = Sc[r2 * 65 + cg + i]; mloc = fmaxf(mloc, sv[i]); }
        mloc = fmaxf(mloc, __shfl_xor(mloc, 1));
        mloc = fmaxf(mloc, __shfl_xor(mloc, 2));
        mloc = fmaxf(mloc, __shfl_xor(mloc, 4));
        float m_old = m_st[r2];
        float m_new = fmaxf(m_old, mloc);
        float alpha = __expf(m_old - m_new);
        float sum = 0.f;
        #pragma unroll
        for (int i = 0; i < 8; ++i) {
            float p = __expf(sv[i] - m_new);
            sum += p;
            Pb[r2 * 80 + cg + i] = f2bf(p);
        }
        sum += __shfl_xor(sum, 1);
        sum += __shfl_xor(sum, 2);
        sum += __shfl_xor(sum, 4);
        if ((lane & 7) == 0) {
            m_st[r2] = m_new;
            l_st[r2] = l_st[r2] * alpha + sum;
            al_st[r2] = alpha;
        }
        __syncthreads();

        // ---- phase 3: O = O*alpha + P V (this wave's 256 d-cols) ----
        #pragma unroll
        for (int rb = 0; rb < 2; ++rb) {
            float a0 = al_st[rb * 16 + quad * 4 + 0];
            float a1 = al_st[rb * 16 + quad * 4 + 1];
            float a2 = al_st[rb * 16 + quad * 4 + 2];
            float a3 = al_st[rb * 16 + quad * 4 + 3];
            #pragma unroll
            for (int dt = 0; dt < 16; ++dt) {
                o_acc[rb][dt][0] *= a0;
                o_acc[rb][dt][1] *= a1;
                o_acc[rb][dt][2] *= a2;
                o_acc[rb][dt][3] *= a3;
            }
        }
        short8 pf[2][2];
        #pragma unroll
        for (int rb = 0; rb < 2; ++rb)
            #pragma unroll
            for (int ks = 0; ks < 2; ++ks)
                pf[rb][ks] = *(const short8*)&Pb[(rb * 16 + l16) * 80 + ks * 32 + quad * 8];
        const u16* vp = vwave + kb;
        #pragma unroll
        for (int dt = 0; dt < 16; ++dt) {
            short8 vf0 = *(const short8*)(vp + (size_t)dt * 16 * SEQ);
            short8 vf1 = *(const short8*)(vp + (size_t)dt * 16 * SEQ + 32);
            #pragma unroll
            for (int rb = 0; rb < 2; ++rb) {
                o_acc[rb][dt] = __builtin_amdgcn_mfma_f32_16x16x32_bf16(pf[rb][0], vf0, o_acc[rb][dt], 0, 0, 0);
                o_acc[rb][dt] = __builtin_amdgcn_mfma_f32_16x16x32_bf16(pf[rb][1], vf1, o_acc[rb][dt], 0, 0, 0);
            }
        }
        // barrier #1 of the next iteration orders phase-3 reads of Pb/al_st
        // against the next phase-2 writes; phase 1 touches only Sc/q_lds.
    }

    // epilogue: O /= l, write f32
    #pragma unroll
    for (int rb = 0; rb < 2; ++rb) {
        #pragma unroll
        for (int rr = 0; rr < 4; ++rr) {
            int row = rb * 16 + quad * 4 + rr;
            float linv = 1.f / l_st[row];
            #pragma unroll
            for (int dt = 0; dt < 16; ++dt) {
                out[((size_t)(b * SEQ + q0 + row)) * HD + w * 256 + dt * 16 + l16] =
                    o_acc[rb][dt][rr] * linv;
            }
        }
    }
}

extern "C" void kernel_launch(void* const* d_in, const int* in_sizes, int n_in,
                              void* d_out, int out_size, void* d_ws, size_t ws_size,
                              hipStream_t stream) {
    const float* x  = (const float*)d_in[0];
    const float* Wq = (const float*)d_in[1];
    const float* bq = (const float*)d_in[2];
    const float* Wk = (const float*)d_in[3];
    const float* bk = (const float*)d_in[4];
    const float* Wv = (const float*)d_in[5];
    const float* bv = (const float*)d_in[6];
    float* out = (float*)d_out;

    char* ws = (char*)d_ws;
    u16* xb  = (u16*)ws;                                   // 32 MB (x as bf16)
    u16* wt  = (u16*)(ws + (size_t)32 * 1024 * 1024);      // 6 MB (3 x 1024^2 bf16)
    u16* qb  = (u16*)(ws + (size_t)38 * 1024 * 1024);      // 32 MB
    u16* kb  = (u16*)(ws + (size_t)70 * 1024 * 1024);      // 32 MB
    u16* vtb = (u16*)(ws + (size_t)102 * 1024 * 1024);     // 32 MB (V transposed per batch)

    cvt_kernel<<<dim3(4096), 256, 0, stream>>>(x, xb, (4 * SEQ * HD) / 4);
    wt_kernel<<<dim3(16, 16, 3), 256, 0, stream>>>(Wq, Wk, Wv, wt);
    qkv_gemm<<<dim3(128, 8, 3), 256, 0, stream>>>(xb, wt, bq, bk, bv, qb, kb, vtb);
    flash_kernel<<<dim3(512), 256, 0, stream>>>(qb, kb, vtb, out);
}

// Round 4
// 1202.291 us; speedup vs baseline: 1.0669x; 1.0047x over previous
//
#include <hip/hip_runtime.h>

typedef unsigned short u16;
typedef __attribute__((ext_vector_type(8))) short short8;
typedef __attribute__((ext_vector_type(4))) short short4v;
typedef __attribute__((ext_vector_type(4))) float floatx4;

#define HD 1024
#define SEQ 4096

__device__ inline u16 f2bf(float f) {
    union { float f; unsigned int i; } c; c.f = f;
    unsigned int r = c.i + 0x7fffu + ((c.i >> 16) & 1u);
    return (u16)(r >> 16);
}

// ---------------- Kernel A: x f32 -> bf16 ----------------
__global__ __launch_bounds__(256) void cvt_kernel(const float* __restrict__ in,
                                                  u16* __restrict__ out, int n4) {
    int idx = blockIdx.x * 256 + threadIdx.x;
    int stride = gridDim.x * 256;
    for (int i = idx; i < n4; i += stride) {
        floatx4 v = ((const floatx4*)in)[i];
        short4v o;
        o[0] = (short)f2bf(v[0]); o[1] = (short)f2bf(v[1]);
        o[2] = (short)f2bf(v[2]); o[3] = (short)f2bf(v[3]);
        ((short4v*)out)[i] = o;
    }
}

// ---------------- Kernel 0: W f32 [k][n] -> Wt bf16 [n][k], 3 matrices ----------------
__global__ __launch_bounds__(256) void wt_kernel(const float* __restrict__ Wq,
                                                 const float* __restrict__ Wk,
                                                 const float* __restrict__ Wv,
                                                 u16* __restrict__ wt) {
    __shared__ u16 tile[64 * 65];
    int z = blockIdx.z;
    const float* W = (z == 0) ? Wq : ((z == 1) ? Wk : Wv);
    u16* out = wt + (size_t)z * HD * HD;
    int k0 = blockIdx.x * 64, n0 = blockIdx.y * 64;
    int t = threadIdx.x;
    int r = t >> 4, c4 = (t & 15) * 4;
    for (int h = 0; h < 4; ++h) {
        int row = r + h * 16;
        floatx4 v = *(const floatx4*)(W + (size_t)(k0 + row) * HD + n0 + c4);
        tile[row * 65 + c4 + 0] = f2bf(v[0]);
        tile[row * 65 + c4 + 1] = f2bf(v[1]);
        tile[row * 65 + c4 + 2] = f2bf(v[2]);
        tile[row * 65 + c4 + 3] = f2bf(v[3]);
    }
    __syncthreads();
    int r2 = t >> 3, c8 = (t & 7) * 8;
    union { short8 v; u16 u[8]; } buf;
    for (int h = 0; h < 2; ++h) {
        int rr = r2 + h * 32;
        #pragma unroll
        for (int i = 0; i < 8; ++i) buf.u[i] = tile[(c8 + i) * 65 + rr];
        *(short8*)(out + (size_t)(n0 + rr) * HD + k0 + c8) = buf.v;
    }
}

// ---------------- Kernel 1: QKV GEMM (bf16 in, f32 bias, bf16 out) ----------------
__global__ __launch_bounds__(256, 2) void qkv_gemm(const u16* __restrict__ x,
                                                   const u16* __restrict__ wt,
                                                   const float* __restrict__ bq,
                                                   const float* __restrict__ bk,
                                                   const float* __restrict__ bv,
                                                   u16* __restrict__ qb,
                                                   u16* __restrict__ kbuf,
                                                   u16* __restrict__ vtb) {
    __shared__ __align__(16) u16 sA[128 * 40];
    __shared__ __align__(16) u16 sB[128 * 40];
    int z = blockIdx.z;
    const u16* Bt = wt + (size_t)z * HD * HD;
    const float* bias = (z == 0) ? bq : ((z == 1) ? bk : bv);
    int m0 = blockIdx.x * 128, n0 = blockIdx.y * 128;
    int t = threadIdx.x, lane = t & 63, w = t >> 6;
    int quad = lane >> 4, l16 = lane & 15;
    int wm = w >> 1, wn = w & 1;
    floatx4 acc[4][4] = {};
    int sr = t >> 2, sc = (t & 3) * 8;

    for (int k0 = 0; k0 < HD; k0 += 32) {
        #pragma unroll
        for (int h = 0; h < 2; ++h) {
            int row = sr + h * 64;
            *(short8*)&sA[row * 40 + sc] = *(const short8*)&x[(size_t)(m0 + row) * HD + k0 + sc];
            *(short8*)&sB[row * 40 + sc] = *(const short8*)&Bt[(size_t)(n0 + row) * HD + k0 + sc];
        }
        __syncthreads();
        short8 af[4], bfr[4];
        #pragma unroll
        for (int i = 0; i < 4; ++i) af[i] = *(const short8*)&sA[(wm * 64 + i * 16 + l16) * 40 + quad * 8];
        #pragma unroll
        for (int j = 0; j < 4; ++j) bfr[j] = *(const short8*)&sB[(wn * 64 + j * 16 + l16) * 40 + quad * 8];
        #pragma unroll
        for (int i = 0; i < 4; ++i)
            #pragma unroll
            for (int j = 0; j < 4; ++j)
                acc[i][j] = __builtin_amdgcn_mfma_f32_16x16x32_bf16(af[i], bfr[j], acc[i][j], 0, 0, 0);
        __syncthreads();
    }

    #pragma unroll
    for (int j = 0; j < 4; ++j) {
        int n = n0 + wn * 64 + j * 16 + l16;
        float bb = bias[n];
        #pragma unroll
        for (int i = 0; i < 4; ++i) {
            #pragma unroll
            for (int rr = 0; rr < 4; ++rr) {
                int m = m0 + wm * 64 + i * 16 + quad * 4 + rr;
                u16 h = f2bf(acc[i][j][rr] + bb);
                if (z == 0) {
                    qb[(size_t)m * HD + n] = h;
                } else if (z == 1) {
                    kbuf[(size_t)m * HD + n] = h;
                } else {
                    int b = m >> 12, s = m & 4095;
                    vtb[((size_t)(b * HD + n)) * SEQ + s] = h;
                }
            }
        }
    }
}

// ---------------- Kernel 2: flash attention (bf16 in, f32 out) ----------------
// Mq=32/block, grid 512 (2 blocks/CU), 4 waves.
// XCD swizzle: xcd = bid&7 -> batch = xcd>>1. Each XCD streams ONE batch's
// K/V (16 MB, ~256KB active window) -> tiles stay L2-resident instead of L3.
// V loads for dt 0..7 are prefetched at phase-1 start: they drain at the
// phase-1 barrier alongside the K loads, so phase 3 starts with half its V
// data already in registers.
__global__ __launch_bounds__(256, 2) void flash_kernel(const u16* __restrict__ q,
                                                       const u16* __restrict__ k,
                                                       const u16* __restrict__ vt,
                                                       float* __restrict__ out) {
    __shared__ __align__(16) u16 q_lds[32 * 1032];  // row stride 2064B = 129*16B (odd) -> conflict-free b128
    __shared__ float Sc[32 * 65];
    __shared__ __align__(16) u16 Pb[32 * 80];
    __shared__ float m_st[32], l_st[32], al_st[32];

    int t = threadIdx.x, lane = t & 63, w = t >> 6;
    int quad = lane >> 4, l16 = lane & 15;
    int bid = blockIdx.x;
    int xcd = bid & 7, j = bid >> 3;
    int b = xcd >> 1;                       // 2 XCDs per batch
    int q0 = (j * 2 + (xcd & 1)) * 32;      // 128 distinct q-tiles per batch

    // stage Q tile [32 x 1024]
    for (int i = t; i < 32 * 128; i += 256) {
        int r = i >> 7, c8 = (i & 127) * 8;
        *(short8*)&q_lds[r * 1032 + c8] =
            *(const short8*)&q[((size_t)(b * SEQ + q0 + r)) * HD + c8];
    }
    if (t < 32) { m_st[t] = -1e30f; l_st[t] = 0.f; }
    floatx4 o_acc[2][16] = {};
    __syncthreads();

    const u16* kwave = k + ((size_t)(b * SEQ + w * 16 + l16)) * HD + quad * 8;
    const u16* vwave = vt + ((size_t)(b * HD + w * 256 + l16)) * SEQ + quad * 8;
    int r2 = w * 8 + (lane >> 3);
    int cg = (lane & 7) * 8;

    for (int tt = 0; tt < 64; ++tt) {
        int kb = tt * 64;
        const u16* vp = vwave + kb;

        // ---- V prefetch (dt 0..7): hidden behind phase 1 + softmax ----
        short8 vpre[8][2];
        #pragma unroll
        for (int dt = 0; dt < 8; ++dt) {
            vpre[dt][0] = *(const short8*)(vp + (size_t)dt * 16 * SEQ);
            vpre[dt][1] = *(const short8*)(vp + (size_t)dt * 16 * SEQ + 32);
        }

        // ---- phase 1: S = Q K^T (this wave's 16 k-cols) ----
        floatx4 s_acc[2] = {};
        const u16* kp = kwave + (size_t)kb * HD;
        #pragma unroll 8
        for (int ks = 0; ks < 32; ++ks) {
            short8 kf = *(const short8*)(kp + ks * 32);
            #pragma unroll
            for (int rb = 0; rb < 2; ++rb) {
                short8 qf = *(const short8*)&q_lds[(rb * 16 + l16) * 1032 + ks * 32 + quad * 8];
                s_acc[rb] = __builtin_amdgcn_mfma_f32_16x16x32_bf16(qf, kf, s_acc[rb], 0, 0, 0);
            }
        }
        #pragma unroll
        for (int rb = 0; rb < 2; ++rb)
            #pragma unroll
            for (int rr = 0; rr < 4; ++rr)
                Sc[(rb * 16 + quad * 4 + rr) * 65 + w * 16 + l16] = s_acc[rb][rr] * 0.03125f;
        __syncthreads();

        // ---- phase 2: online softmax (row r2, 8 cols per lane) ----
        float sv[8];
        float mloc = -1e30f;
        #pragma unroll
        for (int i = 0; i < 8; ++i) { sv[i] = Sc[r2 * 65 + cg + i]; mloc = fmaxf(mloc, sv[i]); }
        mloc = fmaxf(mloc, __shfl_xor(mloc, 1));
        mloc = fmaxf(mloc, __shfl_xor(mloc, 2));
        mloc = fmaxf(mloc, __shfl_xor(mloc, 4));
        float m_old = m_st[r2];
        float m_new = fmaxf(m_old, mloc);
        float alpha = __expf(m_old - m_new);
        float sum = 0.f;
        #pragma unroll
        for (int i = 0; i < 8; ++i) {
            float p = __expf(sv[i] - m_new);
            sum += p;
            Pb[r2 * 80 + cg + i] = f2bf(p);
        }
        sum += __shfl_xor(sum, 1);
        sum += __shfl_xor(sum, 2);
        sum += __shfl_xor(sum, 4);
        if ((lane & 7) == 0) {
            m_st[r2] = m_new;
            l_st[r2] = l_st[r2] * alpha + sum;
            al_st[r2] = alpha;
        }
        __syncthreads();

        // ---- phase 3: O = O*alpha + P V (this wave's 256 d-cols) ----
        #pragma unroll
        for (int rb = 0; rb < 2; ++rb) {
            float a0 = al_st[rb * 16 + quad * 4 + 0];
            float a1 = al_st[rb * 16 + quad * 4 + 1];
            float a2 = al_st[rb * 16 + quad * 4 + 2];
            float a3 = al_st[rb * 16 + quad * 4 + 3];
            #pragma unroll
            for (int dt = 0; dt < 16; ++dt) {
                o_acc[rb][dt][0] *= a0;
                o_acc[rb][dt][1] *= a1;
                o_acc[rb][dt][2] *= a2;
                o_acc[rb][dt][3] *= a3;
            }
        }
        short8 pf[2][2];
        #pragma unroll
        for (int rb = 0; rb < 2; ++rb)
            #pragma unroll
            for (int ks = 0; ks < 2; ++ks)
                pf[rb][ks] = *(const short8*)&Pb[(rb * 16 + l16) * 80 + ks * 32 + quad * 8];
        #pragma unroll
        for (int dt = 0; dt < 8; ++dt) {
            #pragma unroll
            for (int rb = 0; rb < 2; ++rb) {
                o_acc[rb][dt] = __builtin_amdgcn_mfma_f32_16x16x32_bf16(pf[rb][0], vpre[dt][0], o_acc[rb][dt], 0, 0, 0);
                o_acc[rb][dt] = __builtin_amdgcn_mfma_f32_16x16x32_bf16(pf[rb][1], vpre[dt][1], o_acc[rb][dt], 0, 0, 0);
            }
        }
        #pragma unroll
        for (int dt = 8; dt < 16; ++dt) {
            short8 vf0 = *(const short8*)(vp + (size_t)dt * 16 * SEQ);
            short8 vf1 = *(const short8*)(vp + (size_t)dt * 16 * SEQ + 32);
            #pragma unroll
            for (int rb = 0; rb < 2; ++rb) {
                o_acc[rb][dt] = __builtin_amdgcn_mfma_f32_16x16x32_bf16(pf[rb][0], vf0, o_acc[rb][dt], 0, 0, 0);
                o_acc[rb][dt] = __builtin_amdgcn_mfma_f32_16x16x32_bf16(pf[rb][1], vf1, o_acc[rb][dt], 0, 0, 0);
            }
        }
        // barrier #1 of the next iteration orders phase-3 reads of Pb/al_st
        // against the next phase-2 writes; phase 1 touches only Sc/q_lds.
    }

    // epilogue: O /= l, write f32
    #pragma unroll
    for (int rb = 0; rb < 2; ++rb) {
        #pragma unroll
        for (int rr = 0; rr < 4; ++rr) {
            int row = rb * 16 + quad * 4 + rr;
            float linv = 1.f / l_st[row];
            #pragma unroll
            for (int dt = 0; dt < 16; ++dt) {
                out[((size_t)(b * SEQ + q0 + row)) * HD + w * 256 + dt * 16 + l16] =
                    o_acc[rb][dt][rr] * linv;
            }
        }
    }
}

extern "C" void kernel_launch(void* const* d_in, const int* in_sizes, int n_in,
                              void* d_out, int out_size, void* d_ws, size_t ws_size,
                              hipStream_t stream) {
    const float* x  = (const float*)d_in[0];
    const float* Wq = (const float*)d_in[1];
    const float* bq = (const float*)d_in[2];
    const float* Wk = (const float*)d_in[3];
    const float* bk = (const float*)d_in[4];
    const float* Wv = (const float*)d_in[5];
    const float* bv = (const float*)d_in[6];
    float* out = (float*)d_out;

    char* ws = (char*)d_ws;
    u16* xb  = (u16*)ws;                                   // 32 MB (x as bf16)
    u16* wt  = (u16*)(ws + (size_t)32 * 1024 * 1024);      // 6 MB
    u16* qb  = (u16*)(ws + (size_t)38 * 1024 * 1024);      // 32 MB
    u16* kb  = (u16*)(ws + (size_t)70 * 1024 * 1024);      // 32 MB
    u16* vtb = (u16*)(ws + (size_t)102 * 1024 * 1024);     // 32 MB (V transposed per batch)

    cvt_kernel<<<dim3(4096), 256, 0, stream>>>(x, xb, (4 * SEQ * HD) / 4);
    wt_kernel<<<dim3(16, 16, 3), 256, 0, stream>>>(Wq, Wk, Wv, wt);
    qkv_gemm<<<dim3(128, 8, 3), 256, 0, stream>>>(xb, wt, bq, bk, bv, qb, kb, vtb);
    flash_kernel<<<dim3(512), 256, 0, stream>>>(qb, kb, vtb, out);
}

// Round 5
// 830.290 us; speedup vs baseline: 1.5449x; 1.4480x over previous
//
#include <hip/hip_runtime.h>

typedef unsigned short u16;
typedef __attribute__((ext_vector_type(8))) short short8;
typedef __attribute__((ext_vector_type(4))) short short4v;
typedef __attribute__((ext_vector_type(4))) float floatx4;

#define HD 1024
#define SEQ 4096

__device__ inline u16 f2bf(float f) {
    union { float f; unsigned int i; } c; c.f = f;
    unsigned int r = c.i + 0x7fffu + ((c.i >> 16) & 1u);
    return (u16)(r >> 16);
}

// ---------------- Kernel A: x f32 -> bf16 ----------------
__global__ __launch_bounds__(256) void cvt_kernel(const float* __restrict__ in,
                                                  u16* __restrict__ out, int n4) {
    int idx = blockIdx.x * 256 + threadIdx.x;
    int stride = gridDim.x * 256;
    for (int i = idx; i < n4; i += stride) {
        floatx4 v = ((const floatx4*)in)[i];
        short4v o;
        o[0] = (short)f2bf(v[0]); o[1] = (short)f2bf(v[1]);
        o[2] = (short)f2bf(v[2]); o[3] = (short)f2bf(v[3]);
        ((short4v*)out)[i] = o;
    }
}

// ---------------- Kernel 0: W f32 [k][n] -> Wt bf16 [n][k], 3 matrices ----------------
__global__ __launch_bounds__(256) void wt_kernel(const float* __restrict__ Wq,
                                                 const float* __restrict__ Wk,
                                                 const float* __restrict__ Wv,
                                                 u16* __restrict__ wt) {
    __shared__ u16 tile[64 * 65];
    int z = blockIdx.z;
    const float* W = (z == 0) ? Wq : ((z == 1) ? Wk : Wv);
    u16* out = wt + (size_t)z * HD * HD;
    int k0 = blockIdx.x * 64, n0 = blockIdx.y * 64;
    int t = threadIdx.x;
    int r = t >> 4, c4 = (t & 15) * 4;
    for (int h = 0; h < 4; ++h) {
        int row = r + h * 16;
        floatx4 v = *(const floatx4*)(W + (size_t)(k0 + row) * HD + n0 + c4);
        tile[row * 65 + c4 + 0] = f2bf(v[0]);
        tile[row * 65 + c4 + 1] = f2bf(v[1]);
        tile[row * 65 + c4 + 2] = f2bf(v[2]);
        tile[row * 65 + c4 + 3] = f2bf(v[3]);
    }
    __syncthreads();
    int r2 = t >> 3, c8 = (t & 7) * 8;
    union { short8 v; u16 u[8]; } buf;
    for (int h = 0; h < 2; ++h) {
        int rr = r2 + h * 32;
        #pragma unroll
        for (int i = 0; i < 8; ++i) buf.u[i] = tile[(c8 + i) * 65 + rr];
        *(short8*)(out + (size_t)(n0 + rr) * HD + k0 + c8) = buf.v;
    }
}

// ---------------- Kernel 1: QKV GEMM (bf16 in, f32 bias, bf16 out) ----------------
__global__ __launch_bounds__(256, 2) void qkv_gemm(const u16* __restrict__ x,
                                                   const u16* __restrict__ wt,
                                                   const float* __restrict__ bq,
                                                   const float* __restrict__ bk,
                                                   const float* __restrict__ bv,
                                                   u16* __restrict__ qb,
                                                   u16* __restrict__ kbuf,
                                                   u16* __restrict__ vtb) {
    __shared__ __align__(16) u16 sA[128 * 40];
    __shared__ __align__(16) u16 sB[128 * 40];
    int z = blockIdx.z;
    const u16* Bt = wt + (size_t)z * HD * HD;
    const float* bias = (z == 0) ? bq : ((z == 1) ? bk : bv);
    int m0 = blockIdx.x * 128, n0 = blockIdx.y * 128;
    int t = threadIdx.x, lane = t & 63, w = t >> 6;
    int quad = lane >> 4, l16 = lane & 15;
    int wm = w >> 1, wn = w & 1;
    floatx4 acc[4][4] = {};
    int sr = t >> 2, sc = (t & 3) * 8;

    for (int k0 = 0; k0 < HD; k0 += 32) {
        #pragma unroll
        for (int h = 0; h < 2; ++h) {
            int row = sr + h * 64;
            *(short8*)&sA[row * 40 + sc] = *(const short8*)&x[(size_t)(m0 + row) * HD + k0 + sc];
            *(short8*)&sB[row * 40 + sc] = *(const short8*)&Bt[(size_t)(n0 + row) * HD + k0 + sc];
        }
        __syncthreads();
        short8 af[4], bfr[4];
        #pragma unroll
        for (int i = 0; i < 4; ++i) af[i] = *(const short8*)&sA[(wm * 64 + i * 16 + l16) * 40 + quad * 8];
        #pragma unroll
        for (int j = 0; j < 4; ++j) bfr[j] = *(const short8*)&sB[(wn * 64 + j * 16 + l16) * 40 + quad * 8];
        #pragma unroll
        for (int i = 0; i < 4; ++i)
            #pragma unroll
            for (int j = 0; j < 4; ++j)
                acc[i][j] = __builtin_amdgcn_mfma_f32_16x16x32_bf16(af[i], bfr[j], acc[i][j], 0, 0, 0);
        __syncthreads();
    }

    #pragma unroll
    for (int j = 0; j < 4; ++j) {
        int n = n0 + wn * 64 + j * 16 + l16;
        float bb = bias[n];
        #pragma unroll
        for (int i = 0; i < 4; ++i) {
            #pragma unroll
            for (int rr = 0; rr < 4; ++rr) {
                int m = m0 + wm * 64 + i * 16 + quad * 4 + rr;
                u16 h = f2bf(acc[i][j][rr] + bb);
                if (z == 0) {
                    qb[(size_t)m * HD + n] = h;
                } else if (z == 1) {
                    kbuf[(size_t)m * HD + n] = h;
                } else {
                    int b = m >> 12, s = m & 4095;
                    vtb[((size_t)(b * HD + n)) * SEQ + s] = h;
                }
            }
        }
    }
}

// ---------------- Kernel 2: flash attention (bf16 in, f32 out) ----------------
// Mq=64/block, 512 threads (8 waves), grid 256 (1 block/CU, 2 waves/SIMD).
// Halves K/V re-read traffic vs Mq=32 (the L2/L3-path ceiling, ~8.6 TB/s).
// Phase 1: wave w -> kcol group j=w&3 (16 k-cols), hidden half hh=w>>2 (512 of
//   1024). Each wave loads a DISTINCT 16KB K chunk (no duplication) and
//   computes partial S[64x16]; halves combine in-place in Sc (write, barrier,
//   add, barrier).
// Phase 2: 512 lanes, 8 lanes/row, online softmax, P bf16 -> Pb.
// Phase 3: wave w owns d-slice w*128; o_acc 128 VGPRs; V loads line-optimal.
__global__ __launch_bounds__(512, 2) void flash_kernel(const u16* __restrict__ q,
                                                       const u16* __restrict__ k,
                                                       const u16* __restrict__ vt,
                                                       float* __restrict__ out) {
    __shared__ __align__(16) u16 q_lds[64 * 1032];  // 132096 B; stride 2064B -> 2-way banks (free)
    __shared__ float Sc[64 * 66];                    // 16896 B
    __shared__ __align__(16) u16 Pb[64 * 72];        // 9216 B; 144B row stride, 16B aligned
    __shared__ float m_st[64], l_st[64], al_st[64];  // 768 B   => total 158976 B

    int t = threadIdx.x, lane = t & 63, w = t >> 6;
    int quad = lane >> 4, l16 = lane & 15;
    int j = w & 3, hh = w >> 2;
    int bid = blockIdx.x;
    int xcd = bid & 7;
    int b = xcd >> 1;                          // 2 XCDs per batch
    int q0 = (((bid >> 3) << 1) + (xcd & 1)) * 64;  // 64 q-tiles per batch

    // stage Q tile [64 x 1024]
    for (int i = t; i < 64 * 128; i += 512) {
        int r = i >> 7, c8 = (i & 127) * 8;
        *(short8*)&q_lds[r * 1032 + c8] =
            *(const short8*)&q[((size_t)(b * SEQ + q0 + r)) * HD + c8];
    }
    if (t < 64) { m_st[t] = -1e30f; l_st[t] = 0.f; }
    floatx4 o_acc[4][8] = {};
    __syncthreads();

    const u16* kwave = k + ((size_t)(b * SEQ + j * 16 + l16)) * HD + hh * 512 + quad * 8;
    const u16* vwave = vt + ((size_t)(b * HD + w * 128 + l16)) * SEQ + quad * 8;
    int r2 = t >> 3;                // 64 rows, 8 lanes each
    int cg = (t & 7) * 8;           // 8 cols per lane

    for (int tt = 0; tt < 64; ++tt) {
        int kb = tt * 64;
        // ---- phase 1: partial S = Q_slice K_slice^T (16 k-cols, 512 h) ----
        floatx4 s_acc[4] = {};
        const u16* kp = kwave + (size_t)kb * HD;
        #pragma unroll 4
        for (int ks = 0; ks < 16; ++ks) {
            short8 kf = *(const short8*)(kp + ks * 32);
            #pragma unroll
            for (int rb = 0; rb < 4; ++rb) {
                short8 qf = *(const short8*)&q_lds[(rb * 16 + l16) * 1032 + hh * 512 + ks * 32 + quad * 8];
                s_acc[rb] = __builtin_amdgcn_mfma_f32_16x16x32_bf16(qf, kf, s_acc[rb], 0, 0, 0);
            }
        }
        if (hh == 0) {
            #pragma unroll
            for (int rb = 0; rb < 4; ++rb)
                #pragma unroll
                for (int rr = 0; rr < 4; ++rr)
                    Sc[(rb * 16 + quad * 4 + rr) * 66 + j * 16 + l16] = s_acc[rb][rr] * 0.03125f;
        }
        __syncthreads();
        if (hh == 1) {
            #pragma unroll
            for (int rb = 0; rb < 4; ++rb)
                #pragma unroll
                for (int rr = 0; rr < 4; ++rr)
                    Sc[(rb * 16 + quad * 4 + rr) * 66 + j * 16 + l16] += s_acc[rb][rr] * 0.03125f;
        }
        __syncthreads();

        // ---- phase 2: online softmax (row r2, 8 cols per lane) ----
        float sv[8];
        float mloc = -1e30f;
        #pragma unroll
        for (int i = 0; i < 8; ++i) { sv[i] = Sc[r2 * 66 + cg + i]; mloc = fmaxf(mloc, sv[i]); }
        mloc = fmaxf(mloc, __shfl_xor(mloc, 1));
        mloc = fmaxf(mloc, __shfl_xor(mloc, 2));
        mloc = fmaxf(mloc, __shfl_xor(mloc, 4));
        float m_old = m_st[r2];
        float m_new = fmaxf(m_old, mloc);
        float alpha = __expf(m_old - m_new);
        float sum = 0.f;
        #pragma unroll
        for (int i = 0; i < 8; ++i) {
            float p = __expf(sv[i] - m_new);
            sum += p;
            Pb[r2 * 72 + cg + i] = f2bf(p);
        }
        sum += __shfl_xor(sum, 1);
        sum += __shfl_xor(sum, 2);
        sum += __shfl_xor(sum, 4);
        if ((t & 7) == 0) {
            m_st[r2] = m_new;
            l_st[r2] = l_st[r2] * alpha + sum;
            al_st[r2] = alpha;
        }
        __syncthreads();

        // ---- phase 3: O = O*alpha + P V (this wave's 128 d-cols) ----
        #pragma unroll
        for (int rb = 0; rb < 4; ++rb) {
            float a0 = al_st[rb * 16 + quad * 4 + 0];
            float a1 = al_st[rb * 16 + quad * 4 + 1];
            float a2 = al_st[rb * 16 + quad * 4 + 2];
            float a3 = al_st[rb * 16 + quad * 4 + 3];
            #pragma unroll
            for (int dt = 0; dt < 8; ++dt) {
                o_acc[rb][dt][0] *= a0;
                o_acc[rb][dt][1] *= a1;
                o_acc[rb][dt][2] *= a2;
                o_acc[rb][dt][3] *= a3;
            }
        }
        short8 pf[4][2];
        #pragma unroll
        for (int rb = 0; rb < 4; ++rb)
            #pragma unroll
            for (int ks2 = 0; ks2 < 2; ++ks2)
                pf[rb][ks2] = *(const short8*)&Pb[(rb * 16 + l16) * 72 + ks2 * 32 + quad * 8];
        const u16* vp = vwave + kb;
        #pragma unroll
        for (int dt = 0; dt < 8; ++dt) {
            short8 vf0 = *(const short8*)(vp + (size_t)dt * 16 * SEQ);
            short8 vf1 = *(const short8*)(vp + (size_t)dt * 16 * SEQ + 32);
            #pragma unroll
            for (int rb = 0; rb < 4; ++rb) {
                o_acc[rb][dt] = __builtin_amdgcn_mfma_f32_16x16x32_bf16(pf[rb][0], vf0, o_acc[rb][dt], 0, 0, 0);
                o_acc[rb][dt] = __builtin_amdgcn_mfma_f32_16x16x32_bf16(pf[rb][1], vf1, o_acc[rb][dt], 0, 0, 0);
            }
        }
        // next iteration's barriers order phase-3 reads of Pb/al_st against
        // the next phase-2 writes; phase 1 touches only Sc/q_lds.
    }

    // epilogue: O /= l, write f32
    #pragma unroll
    for (int rb = 0; rb < 4; ++rb) {
        #pragma unroll
        for (int rr = 0; rr < 4; ++rr) {
            int row = rb * 16 + quad * 4 + rr;
            float linv = 1.f / l_st[row];
            #pragma unroll
            for (int dt = 0; dt < 8; ++dt) {
                out[((size_t)(b * SEQ + q0 + row)) * HD + w * 128 + dt * 16 + l16] =
                    o_acc[rb][dt][rr] * linv;
            }
        }
    }
}

extern "C" void kernel_launch(void* const* d_in, const int* in_sizes, int n_in,
                              void* d_out, int out_size, void* d_ws, size_t ws_size,
                              hipStream_t stream) {
    const float* x  = (const float*)d_in[0];
    const float* Wq = (const float*)d_in[1];
    const float* bq = (const float*)d_in[2];
    const float* Wk = (const float*)d_in[3];
    const float* bk = (const float*)d_in[4];
    const float* Wv = (const float*)d_in[5];
    const float* bv = (const float*)d_in[6];
    float* out = (float*)d_out;

    char* ws = (char*)d_ws;
    u16* xb  = (u16*)ws;                                   // 32 MB (x as bf16)
    u16* wt  = (u16*)(ws + (size_t)32 * 1024 * 1024);      // 6 MB
    u16* qb  = (u16*)(ws + (size_t)38 * 1024 * 1024);      // 32 MB
    u16* kb  = (u16*)(ws + (size_t)70 * 1024 * 1024);      // 32 MB
    u16* vtb = (u16*)(ws + (size_t)102 * 1024 * 1024);     // 32 MB (V transposed per batch)

    cvt_kernel<<<dim3(4096), 256, 0, stream>>>(x, xb, (4 * SEQ * HD) / 4);
    wt_kernel<<<dim3(16, 16, 3), 256, 0, stream>>>(Wq, Wk, Wv, wt);
    qkv_gemm<<<dim3(128, 8, 3), 256, 0, stream>>>(xb, wt, bq, bk, bv, qb, kb, vtb);
    flash_kernel<<<dim3(256), 512, 0, stream>>>(qb, kb, vtb, out);
}